// Round 3
// baseline (166.572 us; speedup 1.0000x reference)
//
#include <hip/hip_runtime.h>
#include <hip/hip_cooperative_groups.h>
#include <math.h>

namespace cg = cooperative_groups;

static constexpr int Dd    = 128;
static constexpr int NH    = 8;
static constexpr int NE    = 256;
static constexpr int RR    = 32;
static constexpr int TT    = 512;
static constexpr int NTOK  = 2048;
static constexpr int SLOTS = 256;
#define EPSF 1e-6f

__device__ __forceinline__ float elu1(float v) { return v > 0.f ? v + 1.f : expf(v); }
__device__ __forceinline__ float sigm(float v) { return 1.f / (1.f + expf(-v)); }

struct Params {
  const float *x, *g1, *qW, *qb, *kdW, *kdb, *kuW, *kub, *oW, *ob, *rot, *tqs;
  const float *s1W, *s1b, *s2W, *s2b, *g2, *gateW, *gateb, *expW, *m1W, *m1b, *m2W, *m2b;
  float *out;
  float *ctx, *ksum, *h2buf, *oR, *bR, *ybuf;
  int *cnt, *slottok;
};

// ============================================================================
// Fused cooperative kernel, templated on tokens-per-block (TPB = 4 or 8).
// TPB=4 -> 512 blocks (needs 2 blocks/CU resident); TPB=8 -> 256 blocks
// (1 block/CU, guaranteed co-resident). Phases 1/3/5 loop over NG=TPB/4
// groups of 4 tokens; q/k/v state persists in LDS, x/xn in registers.
// ============================================================================
template <int TPB>
__device__ __forceinline__ void fused_body(const Params P) {
  constexpr int NG    = TPB / 4;
  constexpr int GRIDB = NTOK / TPB;
  constexpr int BPE   = GRIDB / NE;    // blocks per expert (2 or 1)
  const int tid = threadIdx.x;
  const int bid = blockIdx.x;
  const int j = tid & 127, g = tid >> 7;
  const int lane = tid & 63;
  const int base_n0 = bid * TPB;
  const int b = base_n0 >> 9;          // batch index

  __shared__ float4 h1T[128];
  __shared__ float4 bufQ[NG][128];     // q per group; later quant result
  __shared__ float4 bufB[128];
  __shared__ float4 part[3][128];
  __shared__ float4 kpart[8][32];
  __shared__ float4 kdT[32];
  __shared__ float4 kupart[256];       // also gate partials
  __shared__ float4 rtmp[2];
  __shared__ __align__(16) float kS[NG][8][16][4];  // k[h][d][tok], elu'd
  __shared__ __align__(16) float vS[NG][8][16][4];  // v[h][e][tok]
  __shared__ float wvS[4][4]; __shared__ int wiS[4][4];
  __shared__ float zS[4][4];
  __shared__ int sSlot[TPB][2]; __shared__ float sWt[TPB][2];
  __shared__ __align__(16) float hT[128 * 20];
  __shared__ float4 y1T[128], y2T[128], inT[128], sT[128];

  float xv[NG][4];
  float xn[NG][4];
#pragma unroll
  for (int grp = 0; grp < NG; grp++)
#pragma unroll
    for (int t = 0; t < 4; t++) { xv[grp][t] = 0.f; xn[grp][t] = 0.f; }

  // ================= Phase 1: rmsnorm1 + q + kd + ku (+oR/bR) ==============
  if (bid == 0) {  // zero accumulators; ordered before use by grid.sync
    for (int i = tid; i < NH * 4 * 256; i += 512) P.ctx[i] = 0.f;
    P.ksum[tid] = 0.f;
    if (tid < NE) P.cnt[tid] = 0;
  }

  for (int grp = 0; grp < NG; grp++) {
    const int n0 = base_n0 + grp * 4;

    // rmsnorm1
    if (tid < 128) {
      float v[4];
#pragma unroll
      for (int t = 0; t < 4; t++) { xv[grp][t] = P.x[(n0 + t) * Dd + j]; v[t] = xv[grp][t] * xv[grp][t]; }
#pragma unroll
      for (int o = 32; o > 0; o >>= 1) {
#pragma unroll
        for (int t = 0; t < 4; t++) v[t] += __shfl_xor(v[t], o, 64);
      }
      if (lane == 0) rtmp[tid >> 6] = make_float4(v[0], v[1], v[2], v[3]);
    }
    __syncthreads();
    if (tid < 128) {
      float g1j = P.g1[j];
#pragma unroll
      for (int t = 0; t < 4; t++) {
        float ss = ((const float*)&rtmp[0])[t] + ((const float*)&rtmp[1])[t];
        ((float*)&h1T[j])[t] = g1j * xv[grp][t] * rsqrtf(ss * (1.f / 128.f) + EPSF);
      }
    }
    __syncthreads();

    // q GEMV (K-split-4) -> bufQ[grp] (token-transposed, elu applied)
    {
      float a0 = 0, a1 = 0, a2 = 0, a3 = 0;
      const float* Wp = P.qW + (g * 32) * Dd + j;
#pragma unroll 16
      for (int i = 0; i < 32; i++) {
        float4 h4 = h1T[g * 32 + i];
        float w = Wp[i * Dd];
        a0 += h4.x * w; a1 += h4.y * w; a2 += h4.z * w; a3 += h4.w * w;
      }
      if (g) part[g - 1][j] = make_float4(a0, a1, a2, a3);
      __syncthreads();
      if (g == 0) {
        float4 p0 = part[0][j], p1 = part[1][j], p2 = part[2][j];
        float bb = P.qb[j];
        ((float*)&bufQ[grp][j])[0] = elu1(a0 + p0.x + p1.x + p2.x + bb);
        ((float*)&bufQ[grp][j])[1] = elu1(a1 + p0.y + p1.y + p2.y + bb);
        ((float*)&bufQ[grp][j])[2] = elu1(a2 + p0.z + p1.z + p2.z + bb);
        ((float*)&bufQ[grp][j])[3] = elu1(a3 + p0.w + p1.w + p2.w + bb);
      }
      __syncthreads();
    }

    // kd GEMV: 32 cols x 8 K-splits
    if (tid < 256) {
      int col = tid & 31, ksp = tid >> 5;
      float a0 = 0, a1 = 0, a2 = 0, a3 = 0;
      const float* Wp = P.kdW + (ksp * 16) * RR + col;
#pragma unroll
      for (int i = 0; i < 16; i++) {
        float4 h4 = h1T[ksp * 16 + i];
        float w = Wp[i * RR];
        a0 += h4.x * w; a1 += h4.y * w; a2 += h4.z * w; a3 += h4.w * w;
      }
      kpart[ksp][col] = make_float4(a0, a1, a2, a3);
    }
    __syncthreads();
    if (tid < 32) {
      float bb = P.kdb[tid];
      float s0 = bb, s1 = bb, s2 = bb, s3 = bb;
#pragma unroll
      for (int k = 0; k < 8; k++) {
        float4 p = kpart[k][tid];
        s0 += p.x; s1 += p.y; s2 += p.z; s3 += p.w;
      }
      kdT[tid] = make_float4(s0, s1, s2, s3);
    }
    __syncthreads();

    // ku GEMV: 256 cols, K=32 split 2 -> kS[grp]/vS[grp]
    {
      int col = tid & 255, kh = tid >> 8;
      float a0 = 0, a1 = 0, a2 = 0, a3 = 0;
      const float* Wp = P.kuW + (kh * 16) * 256 + col;
#pragma unroll
      for (int r = 0; r < 16; r++) {
        float4 k4 = kdT[kh * 16 + r];
        float w = Wp[r * 256];
        a0 += k4.x * w; a1 += k4.y * w; a2 += k4.z * w; a3 += k4.w * w;
      }
      if (kh) kupart[col] = make_float4(a0, a1, a2, a3);
      __syncthreads();
      if (!kh) {
        float4 p = kupart[col];
        float bb = P.kub[col];
        float v0 = a0 + p.x + bb, v1 = a1 + p.y + bb, v2 = a2 + p.z + bb, v3 = a3 + p.w + bb;
        int h = col >> 5, off = col & 31;
        if (off < 16) {
          kS[grp][h][off][0] = elu1(v0); kS[grp][h][off][1] = elu1(v1);
          kS[grp][h][off][2] = elu1(v2); kS[grp][h][off][3] = elu1(v3);
        } else {
          vS[grp][h][off - 16][0] = v0; vS[grp][h][off - 16][1] = v1;
          vS[grp][h][off - 16][2] = v2; vS[grp][h][off - 16][3] = v3;
        }
      }
    }
    __syncthreads();
  }

  // folded into phase 1: oR = oW@rot (blocks 0..31), bR = ob@rot (block 32)
  if (bid < 32) {
    int idx = bid * 512 + tid;
    int row = idx >> 7, col = idx & 127;
    const float* ow = P.oW + row * 128;
    float acc = 0.f;
#pragma unroll 8
    for (int k = 0; k < 128; k++) acc += ow[k] * P.rot[k * 128 + col];
    P.oR[idx] = acc;
  } else if (bid == 32 && tid < 128) {
    float acc = 0.f;
#pragma unroll 8
    for (int k = 0; k < 128; k++) acc += P.ob[k] * P.rot[k * 128 + tid];
    P.bR[tid] = acc;
  }

  cg::this_grid().sync();

  // ================= Phase 2: ctx/ksum accumulation (atomics) =============
  {
    const int h = tid >> 6;            // one head per wave
    const int d = (tid >> 2) & 15;
    const int e0 = (tid & 3) * 4;
    const int bh = b * NH + h;
    float acc[4] = {0.f, 0.f, 0.f, 0.f};
    float ks = 0.f;
#pragma unroll
    for (int grp = 0; grp < NG; grp++) {
      float4 k4 = *(const float4*)&kS[grp][h][d][0];
      ks += k4.x + k4.y + k4.z + k4.w;
#pragma unroll
      for (int ee = 0; ee < 4; ee++) {
        float4 v4 = *(const float4*)&vS[grp][h][e0 + ee][0];
        acc[ee] += k4.x * v4.x + k4.y * v4.y + k4.z * v4.z + k4.w * v4.w;
      }
    }
    float* cp = P.ctx + bh * 256 + d * 16 + e0;
#pragma unroll
    for (int ee = 0; ee < 4; ee++) atomicAdd(cp + ee, acc[ee]);
    if ((tid & 3) == 0) atomicAdd(&P.ksum[bh * 16 + d], ks);
  }

  cg::this_grid().sync();

  // ========== Phase 3: attn -> oR(+quant) -> s1s2 -> rms2||gate -> top2 ====
  for (int grp = 0; grp < NG; grp++) {
    const int n0 = base_n0 + grp * 4;
    float m1[4]; int i1[4]; float m2[4]; int i2[4];
    float val[4]; float r2v[4];

    // attention apply -> bufB (tid<128, K=16); q in bufQ[grp]
    if (tid < 128) {
      int h = j >> 4, e = j & 15;
      const float* cpt = P.ctx + (b * NH + h) * 256;
      const float* kpt = P.ksum + (b * NH + h) * 16;
      float num[4] = {0, 0, 0, 0}, den[4] = {0, 0, 0, 0};
#pragma unroll
      for (int d = 0; d < 16; d++) {
        float cx = cpt[d * 16 + e], ks = kpt[d];
        float4 q4 = bufQ[grp][h * 16 + d];
        num[0] += q4.x * cx; num[1] += q4.y * cx; num[2] += q4.z * cx; num[3] += q4.w * cx;
        den[0] += q4.x * ks; den[1] += q4.y * ks; den[2] += q4.z * ks; den[3] += q4.w * ks;
      }
#pragma unroll
      for (int t = 0; t < 4; t++) ((float*)&bufB[j])[t] = num[t] / (den[t] + EPSF);
    }
    __syncthreads();

    // z = bufB @ oR + bR; quant -> bufQ[grp] (q is dead now)
    {
      float a0 = 0, a1 = 0, a2 = 0, a3 = 0;
      const float* Wp = P.oR + (g * 32) * Dd + j;
#pragma unroll 16
      for (int i = 0; i < 32; i++) {
        float4 h4 = bufB[g * 32 + i];
        float w = Wp[i * Dd];
        a0 += h4.x * w; a1 += h4.y * w; a2 += h4.z * w; a3 += h4.w * w;
      }
      if (g) part[g - 1][j] = make_float4(a0, a1, a2, a3);
      __syncthreads();
      float tot[4];
      if (g == 0) {
        float4 p0 = part[0][j], p1 = part[1][j], p2 = part[2][j];
        float bb = P.bR[j];
        tot[0] = a0 + p0.x + p1.x + p2.x + bb; tot[1] = a1 + p0.y + p1.y + p2.y + bb;
        tot[2] = a2 + p0.z + p1.z + p2.z + bb; tot[3] = a3 + p0.w + p1.w + p2.w + bb;
        float v[4];
#pragma unroll
        for (int t = 0; t < 4; t++) v[t] = tot[t] * tot[t];
#pragma unroll
        for (int o = 32; o > 0; o >>= 1) {
#pragma unroll
          for (int t = 0; t < 4; t++) v[t] += __shfl_xor(v[t], o, 64);
        }
        if (lane == 0) rtmp[tid >> 6] = make_float4(v[0], v[1], v[2], v[3]);
      }
      __syncthreads();
      if (g == 0) {
        float scj = P.tqs[j];
#pragma unroll
        for (int t = 0; t < 4; t++) {
          float ss = ((const float*)&rtmp[0])[t] + ((const float*)&rtmp[1])[t];
          float mag = sqrtf(ss * (1.f / 128.f) + EPSF);
          float zc = fminf(fmaxf(tot[t], -mag), mag);
          ((float*)&bufQ[grp][j])[t] = zc * scj;
        }
      }
      __syncthreads();
    }

    // s1/s2 dual GEMV on bufQ[grp] -> xn[grp] (+res); bufB = g2*xn; rtmp=sumsq
    {
      float a0 = 0, a1 = 0, a2 = 0, a3 = 0;
      const float* Wp = (g < 2 ? P.s1W : P.s2W) + ((g & 1) * 64) * Dd + j;
#pragma unroll 16
      for (int i = 0; i < 64; i++) {
        float4 h4 = bufQ[grp][(g & 1) * 64 + i];
        float w = Wp[i * Dd];
        a0 += h4.x * w; a1 += h4.y * w; a2 += h4.z * w; a3 += h4.w * w;
      }
      if (g) part[g - 1][j] = make_float4(a0, a1, a2, a3);
      __syncthreads();
      if (g == 0) {
        float b1 = P.s1b[j], b2 = P.s2b[j];
        float4 p0 = part[0][j], p1 = part[1][j], p2 = part[2][j];
        float gv[4], uv[4], v[4];
        gv[0] = a0 + p0.x + b1; gv[1] = a1 + p0.y + b1;
        gv[2] = a2 + p0.z + b1; gv[3] = a3 + p0.w + b1;
        uv[0] = p1.x + p2.x + b2; uv[1] = p1.y + p2.y + b2;
        uv[2] = p1.z + p2.z + b2; uv[3] = p1.w + p2.w + b2;
        float g2j = P.g2[j];
#pragma unroll
        for (int t = 0; t < 4; t++) {
          xn[grp][t] = xv[grp][t] + gv[t] * sigm(gv[t]) * uv[t];  // regs -> phase 5
          ((float*)&bufB[j])[t] = g2j * xn[grp][t];
          v[t] = xn[grp][t] * xn[grp][t];
        }
#pragma unroll
        for (int o = 32; o > 0; o >>= 1) {
#pragma unroll
          for (int t = 0; t < 4; t++) v[t] += __shfl_xor(v[t], o, 64);
        }
        if (lane == 0) rtmp[tid >> 6] = make_float4(v[0], v[1], v[2], v[3]);
      }
      __syncthreads();
    }

    // gate logits (K-split-2, 256 cols); r2 at epilogue; h2buf write
    {
      int col = tid & 255, kh = tid >> 8;
      float a0 = 0, a1 = 0, a2 = 0, a3 = 0;
      const float* Wp = P.gateW + (kh * 64) * NE + col;
#pragma unroll 16
      for (int i = 0; i < 64; i++) {
        float4 h4 = bufB[kh * 64 + i];
        float w = Wp[i * NE];
        a0 += h4.x * w; a1 += h4.y * w; a2 += h4.z * w; a3 += h4.w * w;
      }
      if (kh) kupart[col] = make_float4(a0, a1, a2, a3);
      __syncthreads();
#pragma unroll
      for (int t = 0; t < 4; t++) {
        float ss = ((const float*)&rtmp[0])[t] + ((const float*)&rtmp[1])[t];
        r2v[t] = rsqrtf(ss * (1.f / 128.f) + EPSF);
      }
      if (!kh) {
        float4 p = kupart[col];
        float bb = P.gateb[col];
        val[0] = (a0 + p.x) * r2v[0] + bb; val[1] = (a1 + p.y) * r2v[1] + bb;
        val[2] = (a2 + p.z) * r2v[2] + bb; val[3] = (a3 + p.w) * r2v[3] + bb;
      }
      if (tid < 128) {
#pragma unroll
        for (int t = 0; t < 4; t++)
          P.h2buf[(n0 + t) * Dd + j] = ((const float*)&bufB[j])[t] * r2v[t];
      }
    }
    __syncthreads();

    // top-2 over 256 logits (tid<256)
    {
      if (tid < 256) {
        float bv[4]; int bi[4];
#pragma unroll
        for (int t = 0; t < 4; t++) { bv[t] = val[t]; bi[t] = tid; }
#pragma unroll
        for (int o = 32; o > 0; o >>= 1) {
#pragma unroll
          for (int t = 0; t < 4; t++) {
            float wv = __shfl_xor(bv[t], o, 64);
            int wi = __shfl_xor(bi[t], o, 64);
            if (wv > bv[t] || (wv == bv[t] && wi < bi[t])) { bv[t] = wv; bi[t] = wi; }
          }
        }
        if (lane == 0) {
#pragma unroll
          for (int t = 0; t < 4; t++) { wvS[tid >> 6][t] = bv[t]; wiS[tid >> 6][t] = bi[t]; }
        }
      }
      __syncthreads();
      if (tid < 256) {
#pragma unroll
        for (int t = 0; t < 4; t++) {
          m1[t] = wvS[0][t]; i1[t] = wiS[0][t];
#pragma unroll
          for (int w = 1; w < 4; w++) {
            float cv = wvS[w][t]; int ci = wiS[w][t];
            if (cv > m1[t] || (cv == m1[t] && ci < i1[t])) { m1[t] = cv; i1[t] = ci; }
          }
        }
      }
      __syncthreads();
    }
    {
      if (tid < 256) {
        float bv[4]; int bi[4];
#pragma unroll
        for (int t = 0; t < 4; t++) {
          bv[t] = (tid == i1[t]) ? -INFINITY : val[t];
          bi[t] = tid;
        }
#pragma unroll
        for (int o = 32; o > 0; o >>= 1) {
#pragma unroll
          for (int t = 0; t < 4; t++) {
            float wv = __shfl_xor(bv[t], o, 64);
            int wi = __shfl_xor(bi[t], o, 64);
            if (wv > bv[t] || (wv == bv[t] && wi < bi[t])) { bv[t] = wv; bi[t] = wi; }
          }
        }
        if (lane == 0) {
#pragma unroll
          for (int t = 0; t < 4; t++) { wvS[tid >> 6][t] = bv[t]; wiS[tid >> 6][t] = bi[t]; }
        }
      }
      __syncthreads();
      if (tid < 256) {
#pragma unroll
        for (int t = 0; t < 4; t++) {
          m2[t] = wvS[0][t]; i2[t] = wiS[0][t];
#pragma unroll
          for (int w = 1; w < 4; w++) {
            float cv = wvS[w][t]; int ci = wiS[w][t];
            if (cv > m2[t] || (cv == m2[t] && ci < i2[t])) { m2[t] = cv; i2[t] = ci; }
          }
        }
      }
      __syncthreads();
    }
    {
      if (tid < 256) {
        float v[4];
#pragma unroll
        for (int t = 0; t < 4; t++) v[t] = expf(val[t] - m1[t]);
#pragma unroll
        for (int o = 32; o > 0; o >>= 1) {
#pragma unroll
          for (int t = 0; t < 4; t++) v[t] += __shfl_xor(v[t], o, 64);
        }
        if (lane == 0) {
#pragma unroll
          for (int t = 0; t < 4; t++) zS[tid >> 6][t] = v[t];
        }
      }
      __syncthreads();
    }
    if (tid < 4) {
      int t = tid, tok = n0 + t;
      float Z = zS[0][t] + zS[1][t] + zS[2][t] + zS[3][t];
      float p1 = 1.f / Z;
      float p2 = expf(m2[t] - m1[t]) / Z;
      float s = p1 + p2 + EPSF;
      int e1 = i1[t], e2 = i2[t];
      int s1 = atomicAdd(&P.cnt[e1], 1); if (s1 > SLOTS - 1) s1 = SLOTS - 1;
      int s2 = atomicAdd(&P.cnt[e2], 1); if (s2 > SLOTS - 1) s2 = SLOTS - 1;
      int sl1 = e1 * SLOTS + s1, sl2 = e2 * SLOTS + s2;
      P.slottok[sl1] = tok; P.slottok[sl2] = tok;
      sSlot[grp * 4 + t][0] = sl1; sSlot[grp * 4 + t][1] = sl2;
      sWt[grp * 4 + t][0] = p1 / s; sWt[grp * 4 + t][1] = p2 / s;
    }
    __syncthreads();
  }

  cg::this_grid().sync();

  // ================= Phase 4: experts (BPE blocks/expert) ==================
  {
    const int e = bid / BPE, sub = bid % BPE;
    int n = P.cnt[e]; if (n > SLOTS) n = SLOTS;
    const int base = e * SLOTS;
    const float* Wp = P.expW + (size_t)e * Dd * Dd + j;
    for (int t0 = sub * 16; t0 < n; t0 += BPE * 16) {
      int m = n - t0; if (m > 16) m = 16;
      __syncthreads();
      for (int tt = g; tt < m; tt += 4) {
        int tok = P.slottok[base + t0 + tt];
        hT[j * 20 + tt] = P.h2buf[tok * Dd + j];
      }
      __syncthreads();
      float acc[4] = {0, 0, 0, 0};
#pragma unroll 8
      for (int i = 0; i < 128; i++) {
        float w = Wp[i * Dd];
        float4 h4 = *(const float4*)&hT[i * 20 + g * 4];
        acc[0] += h4.x * w; acc[1] += h4.y * w; acc[2] += h4.z * w; acc[3] += h4.w * w;
      }
#pragma unroll
      for (int k = 0; k < 4; k++) {
        int tt = g * 4 + k;
        if (tt < m) P.ybuf[(size_t)(base + t0 + tt) * Dd + j] = acc[k];
      }
    }
  }

  cg::this_grid().sync();

  // ========== Phase 5: gather y -> swiglu m1/m2 -> out + consensus =========
  for (int grp = 0; grp < NG; grp++) {
    const int n0 = base_n0 + grp * 4;
    {
      const int ti = grp * 4 + g;
      float y1 = P.ybuf[(size_t)sSlot[ti][0] * Dd + j];
      float y2 = P.ybuf[(size_t)sSlot[ti][1] * Dd + j];
      ((float*)&y1T[j])[g] = y1;
      ((float*)&y2T[j])[g] = y2;
      ((float*)&inT[j])[g] = sWt[ti][0] * y1 + sWt[ti][1] * y2;
    }
    __syncthreads();

    {
      float a0 = 0, a1 = 0, a2 = 0, a3 = 0;
      const float* Wp = (g < 2 ? P.m1W : P.m2W) + ((g & 1) * 64) * Dd + j;
#pragma unroll 16
      for (int i = 0; i < 64; i++) {
        float4 h4 = inT[(g & 1) * 64 + i];
        float w = Wp[i * Dd];
        a0 += h4.x * w; a1 += h4.y * w; a2 += h4.z * w; a3 += h4.w * w;
      }
      if (g) part[g - 1][j] = make_float4(a0, a1, a2, a3);
      __syncthreads();
      if (g == 0) {
        float b1 = P.m1b[j], b2 = P.m2b[j];
        float4 p0 = part[0][j], p1 = part[1][j], p2 = part[2][j];
        float gv[4], uv[4];
        gv[0] = a0 + p0.x + b1; gv[1] = a1 + p0.y + b1;
        gv[2] = a2 + p0.z + b1; gv[3] = a3 + p0.w + b1;
        uv[0] = p1.x + p2.x + b2; uv[1] = p1.y + p2.y + b2;
        uv[2] = p1.z + p2.z + b2; uv[3] = p1.w + p2.w + b2;
#pragma unroll
        for (int t = 0; t < 4; t++) {
          float sv = gv[t] * sigm(gv[t]) * uv[t];
          ((float*)&sT[j])[t] = sv;
          P.out[(n0 + t) * Dd + j] = xn[grp][t] + sv;   // xn from regs
        }
      }
      __syncthreads();
    }

    if (tid < 128) {
      float v[4];
#pragma unroll
      for (int t = 0; t < 4; t++) {
        float sv = ((const float*)&sT[j])[t];
        float d1 = ((const float*)&y1T[j])[t] - sv;
        float d2 = ((const float*)&y2T[j])[t] - sv;
        v[t] = sWt[grp * 4 + t][0] * d1 * d1 + sWt[grp * 4 + t][1] * d2 * d2;
      }
#pragma unroll
      for (int o = 32; o > 0; o >>= 1) {
#pragma unroll
        for (int t = 0; t < 4; t++) v[t] += __shfl_xor(v[t], o, 64);
      }
      if (lane == 0) rtmp[tid >> 6] = make_float4(v[0], v[1], v[2], v[3]);
    }
    __syncthreads();
    if (tid < 4) {
      float s = ((const float*)&rtmp[0])[tid] + ((const float*)&rtmp[1])[tid];
      P.out[NTOK * Dd + n0 + tid] = expf(-s * (1.f / 128.f));
    }
    __syncthreads();
  }
}

__global__ __launch_bounds__(512, 4) void k_fused4(Params P) { fused_body<4>(P); }
__global__ __launch_bounds__(512)    void k_fused8(Params P) { fused_body<8>(P); }

// ============================================================================
// Fallback path: the verified 5-kernel pipeline (round-0 baseline, 165 us).
// Used only if the cooperative launch is rejected by the runtime.
// ============================================================================
static constexpr int TPBo = 4;

__global__ __launch_bounds__(512) void k_pre(
    const float* __restrict__ x, const float* __restrict__ g1,
    const float* __restrict__ qW, const float* __restrict__ qb,
    const float* __restrict__ kdW, const float* __restrict__ kdb,
    const float* __restrict__ kuW, const float* __restrict__ kub,
    float* __restrict__ qbuf, float* __restrict__ kvbuf,
    float* __restrict__ ctx, float* __restrict__ ksum, int* __restrict__ cnt) {
  const int tid = threadIdx.x;
  const int j = tid & 127, g = tid >> 7;
  const int lane = tid & 63;
  const int n0 = blockIdx.x * TPBo;

  __shared__ float4 h1T[128];
  __shared__ float4 part[3][128];
  __shared__ float4 kpart[8][32];
  __shared__ float4 kdT[32];
  __shared__ float4 kupart[256];
  __shared__ float4 rtmp[2];

  if (blockIdx.x == 0) {
    for (int i = tid; i < 32 * 256; i += 512) ctx[i] = 0.f;
    ksum[tid] = 0.f;
    if (tid < 256) cnt[tid] = 0;
  }

  float xv[4];
  if (tid < 128) {
    float v[4];
#pragma unroll
    for (int t = 0; t < 4; t++) { xv[t] = x[(n0 + t) * Dd + j]; v[t] = xv[t] * xv[t]; }
#pragma unroll
    for (int o = 32; o > 0; o >>= 1) {
#pragma unroll
      for (int t = 0; t < 4; t++) v[t] += __shfl_xor(v[t], o, 64);
    }
    if (lane == 0) rtmp[tid >> 6] = make_float4(v[0], v[1], v[2], v[3]);
  }
  __syncthreads();
  if (tid < 128) {
    float g1j = g1[j];
#pragma unroll
    for (int t = 0; t < 4; t++) {
      float ss = ((const float*)&rtmp[0])[t] + ((const float*)&rtmp[1])[t];
      ((float*)&h1T[j])[t] = g1j * xv[t] * rsqrtf(ss * (1.f / 128.f) + EPSF);
    }
  }
  __syncthreads();

  {
    float a0 = 0, a1 = 0, a2 = 0, a3 = 0;
    const float* Wp = qW + (g * 32) * Dd + j;
#pragma unroll 16
    for (int i = 0; i < 32; i++) {
      float4 h4 = h1T[g * 32 + i];
      float w = Wp[i * Dd];
      a0 += h4.x * w; a1 += h4.y * w; a2 += h4.z * w; a3 += h4.w * w;
    }
    if (g) part[g - 1][j] = make_float4(a0, a1, a2, a3);
    __syncthreads();
    if (g == 0) {
      float4 p0 = part[0][j], p1 = part[1][j], p2 = part[2][j];
      float bb = qb[j];
      qbuf[(n0 + 0) * Dd + j] = elu1(a0 + p0.x + p1.x + p2.x + bb);
      qbuf[(n0 + 1) * Dd + j] = elu1(a1 + p0.y + p1.y + p2.y + bb);
      qbuf[(n0 + 2) * Dd + j] = elu1(a2 + p0.z + p1.z + p2.z + bb);
      qbuf[(n0 + 3) * Dd + j] = elu1(a3 + p0.w + p1.w + p2.w + bb);
    }
    __syncthreads();
  }

  if (tid < 256) {
    int col = tid & 31, ksp = tid >> 5;
    float a0 = 0, a1 = 0, a2 = 0, a3 = 0;
    const float* Wp = kdW + (ksp * 16) * RR + col;
#pragma unroll
    for (int i = 0; i < 16; i++) {
      float4 h4 = h1T[ksp * 16 + i];
      float w = Wp[i * RR];
      a0 += h4.x * w; a1 += h4.y * w; a2 += h4.z * w; a3 += h4.w * w;
    }
    kpart[ksp][col] = make_float4(a0, a1, a2, a3);
  }
  __syncthreads();
  if (tid < 32) {
    float bb = kdb[tid];
    float s0 = bb, s1 = bb, s2 = bb, s3 = bb;
#pragma unroll
    for (int k = 0; k < 8; k++) {
      float4 p = kpart[k][tid];
      s0 += p.x; s1 += p.y; s2 += p.z; s3 += p.w;
    }
    kdT[tid] = make_float4(s0, s1, s2, s3);
  }
  __syncthreads();

  {
    int col = tid & 255, kh = tid >> 8;
    float a0 = 0, a1 = 0, a2 = 0, a3 = 0;
    const float* Wp = kuW + (kh * 16) * 256 + col;
#pragma unroll
    for (int r = 0; r < 16; r++) {
      float4 k4 = kdT[kh * 16 + r];
      float w = Wp[r * 256];
      a0 += k4.x * w; a1 += k4.y * w; a2 += k4.z * w; a3 += k4.w * w;
    }
    if (kh) kupart[col] = make_float4(a0, a1, a2, a3);
    __syncthreads();
    if (!kh) {
      float4 p = kupart[col];
      float bb = kub[col];
      bool isk = (col & 31) < 16;
      float v0 = a0 + p.x + bb, v1 = a1 + p.y + bb, v2 = a2 + p.z + bb, v3 = a3 + p.w + bb;
      kvbuf[(n0 + 0) * 256 + col] = isk ? elu1(v0) : v0;
      kvbuf[(n0 + 1) * 256 + col] = isk ? elu1(v1) : v1;
      kvbuf[(n0 + 2) * 256 + col] = isk ? elu1(v2) : v2;
      kvbuf[(n0 + 3) * 256 + col] = isk ? elu1(v3) : v3;
    }
  }
}

__global__ __launch_bounds__(256) void k_ctx(const float* __restrict__ kv,
                                             float* __restrict__ ctx,
                                             float* __restrict__ ksum,
                                             const float* __restrict__ oW,
                                             const float* __restrict__ ob,
                                             const float* __restrict__ rot,
                                             float* __restrict__ oR,
                                             float* __restrict__ bR) {
  const int blk = blockIdx.x;
  const int tid = threadIdx.x;
  if (blk < 256) {
    const int bh = blk >> 3, c = blk & 7;
    const int b = bh >> 3, h = bh & 7;
    const int d = tid >> 4, e = tid & 15;
    __shared__ float sh[64 * 32];
#pragma unroll
    for (int r = 0; r < 8; r++) {
      int lin = r * 256 + tid;
      int tok = lin >> 5, off = lin & 31;
      sh[lin] = kv[((b * TT + c * 64 + tok) * 256) + h * 32 + off];
    }
    __syncthreads();
    float acc = 0.f, ks = 0.f;
#pragma unroll 4
    for (int t = 0; t < 64; t++) {
      float kk = sh[t * 32 + d];
      acc += kk * sh[t * 32 + 16 + e];
      ks += kk;
    }
    atomicAdd(&ctx[bh * 256 + d * 16 + e], acc);
    if (e == 0) atomicAdd(&ksum[bh * 16 + d], ks);
  } else if (blk < 320) {
    int idx = (blk - 256) * 256 + tid;
    int row = idx >> 7, col = idx & 127;
    const float* ow = oW + row * 128;
    float acc = 0.f;
#pragma unroll 8
    for (int k = 0; k < 128; k++) acc += ow[k] * rot[k * 128 + col];
    oR[row * 128 + col] = acc;
  } else {
    if (tid < 128) {
      float acc = 0.f;
#pragma unroll 8
      for (int k = 0; k < 128; k++) acc += ob[k] * rot[k * 128 + tid];
      bR[tid] = acc;
    }
  }
}

__global__ __launch_bounds__(512) void k_mid(
    const float* __restrict__ x, const float* __restrict__ qbuf,
    const float* __restrict__ ctx, const float* __restrict__ ksum,
    const float* __restrict__ oR, const float* __restrict__ bR,
    const float* __restrict__ tqs,
    const float* __restrict__ s1W, const float* __restrict__ s1b,
    const float* __restrict__ s2W, const float* __restrict__ s2b,
    const float* __restrict__ g2, const float* __restrict__ gateW,
    const float* __restrict__ gateb,
    float* __restrict__ xnbuf, float* __restrict__ h2buf,
    float* __restrict__ gw, int* __restrict__ tokslot,
    int* __restrict__ slottok, int* __restrict__ cnt) {
  const int tid = threadIdx.x;
  const int j = tid & 127, g = tid >> 7;
  const int lane = tid & 63;
  const int n0 = blockIdx.x * TPBo;
  const int b = n0 >> 9;

  __shared__ float4 bufA[128], bufB[128];
  __shared__ float4 part[3][128];
  __shared__ float4 gpart[256];
  __shared__ float4 rtmp[2];
  __shared__ float wvS[4][4]; __shared__ int wiS[4][4];
  __shared__ float zS[4][4];

  float xres[4];
  if (tid < 128) {
#pragma unroll
    for (int t = 0; t < 4; t++) xres[t] = x[(n0 + t) * Dd + j];
  }

  ((float*)&bufA[j])[g] = qbuf[(n0 + g) * Dd + j];
  __syncthreads();

  if (tid < 128) {
    int h = j >> 4, e = j & 15;
    const float* cpt = ctx + (b * NH + h) * 256;
    const float* kpt = ksum + (b * NH + h) * 16;
    float num[4] = {0, 0, 0, 0}, den[4] = {0, 0, 0, 0};
#pragma unroll
    for (int d = 0; d < 16; d++) {
      float cx = cpt[d * 16 + e], ks = kpt[d];
      float4 q4 = bufA[h * 16 + d];
      num[0] += q4.x * cx; num[1] += q4.y * cx; num[2] += q4.z * cx; num[3] += q4.w * cx;
      den[0] += q4.x * ks; den[1] += q4.y * ks; den[2] += q4.z * ks; den[3] += q4.w * ks;
    }
#pragma unroll
    for (int t = 0; t < 4; t++) ((float*)&bufB[j])[t] = num[t] / (den[t] + EPSF);
  }
  __syncthreads();

  {
    float a0 = 0, a1 = 0, a2 = 0, a3 = 0;
    const float* Wp = oR + (g * 32) * Dd + j;
#pragma unroll 16
    for (int i = 0; i < 32; i++) {
      float4 h4 = bufB[g * 32 + i];
      float w = Wp[i * Dd];
      a0 += h4.x * w; a1 += h4.y * w; a2 += h4.z * w; a3 += h4.w * w;
    }
    if (g) part[g - 1][j] = make_float4(a0, a1, a2, a3);
    __syncthreads();
    float tot[4];
    if (g == 0) {
      float4 p0 = part[0][j], p1 = part[1][j], p2 = part[2][j];
      float bb = bR[j];
      tot[0] = a0 + p0.x + p1.x + p2.x + bb; tot[1] = a1 + p0.y + p1.y + p2.y + bb;
      tot[2] = a2 + p0.z + p1.z + p2.z + bb; tot[3] = a3 + p0.w + p1.w + p2.w + bb;
      float v[4];
#pragma unroll
      for (int t = 0; t < 4; t++) v[t] = tot[t] * tot[t];
#pragma unroll
      for (int o = 32; o > 0; o >>= 1) {
#pragma unroll
        for (int t = 0; t < 4; t++) v[t] += __shfl_xor(v[t], o, 64);
      }
      if (lane == 0) rtmp[tid >> 6] = make_float4(v[0], v[1], v[2], v[3]);
    }
    __syncthreads();
    if (g == 0) {
      float scj = tqs[j];
#pragma unroll
      for (int t = 0; t < 4; t++) {
        float ss = ((const float*)&rtmp[0])[t] + ((const float*)&rtmp[1])[t];
        float mag = sqrtf(ss * (1.f / 128.f) + EPSF);
        float zc = fminf(fmaxf(tot[t], -mag), mag);
        ((float*)&bufA[j])[t] = zc * scj;
      }
    }
    __syncthreads();
  }

  {
    float a0 = 0, a1 = 0, a2 = 0, a3 = 0;
    const float* Wp = (g < 2 ? s1W : s2W) + ((g & 1) * 64) * Dd + j;
#pragma unroll 16
    for (int i = 0; i < 64; i++) {
      float4 h4 = bufA[(g & 1) * 64 + i];
      float w = Wp[i * Dd];
      a0 += h4.x * w; a1 += h4.y * w; a2 += h4.z * w; a3 += h4.w * w;
    }
    if (g) part[g - 1][j] = make_float4(a0, a1, a2, a3);
    __syncthreads();
    if (g == 0) {
      float b1 = s1b[j], b2 = s2b[j];
      float4 p0 = part[0][j], p1 = part[1][j], p2 = part[2][j];
      float gv[4], uv[4], xn[4], v[4];
      gv[0] = a0 + p0.x + b1; gv[1] = a1 + p0.y + b1;
      gv[2] = a2 + p0.z + b1; gv[3] = a3 + p0.w + b1;
      uv[0] = p1.x + p2.x + b2; uv[1] = p1.y + p2.y + b2;
      uv[2] = p1.z + p2.z + b2; uv[3] = p1.w + p2.w + b2;
      float g2j = g2[j];
#pragma unroll
      for (int t = 0; t < 4; t++) {
        xn[t] = xres[t] + gv[t] * sigm(gv[t]) * uv[t];
        xnbuf[(n0 + t) * Dd + j] = xn[t];
        ((float*)&bufB[j])[t] = g2j * xn[t];
        v[t] = xn[t] * xn[t];
      }
#pragma unroll
      for (int o = 32; o > 0; o >>= 1) {
#pragma unroll
        for (int t = 0; t < 4; t++) v[t] += __shfl_xor(v[t], o, 64);
      }
      if (lane == 0) rtmp[tid >> 6] = make_float4(v[0], v[1], v[2], v[3]);
    }
    __syncthreads();
  }

  float val[4];
  float r2[4];
  {
    int col = tid & 255, kh = tid >> 8;
    float a0 = 0, a1 = 0, a2 = 0, a3 = 0;
    const float* Wp = gateW + (kh * 64) * NE + col;
#pragma unroll 16
    for (int i = 0; i < 64; i++) {
      float4 h4 = bufB[kh * 64 + i];
      float w = Wp[i * NE];
      a0 += h4.x * w; a1 += h4.y * w; a2 += h4.z * w; a3 += h4.w * w;
    }
    if (kh) gpart[col] = make_float4(a0, a1, a2, a3);
    __syncthreads();
#pragma unroll
    for (int t = 0; t < 4; t++) {
      float ss = ((const float*)&rtmp[0])[t] + ((const float*)&rtmp[1])[t];
      r2[t] = rsqrtf(ss * (1.f / 128.f) + EPSF);
    }
    if (!kh) {
      float4 p = gpart[col];
      float bb = gateb[col];
      val[0] = (a0 + p.x) * r2[0] + bb; val[1] = (a1 + p.y) * r2[1] + bb;
      val[2] = (a2 + p.z) * r2[2] + bb; val[3] = (a3 + p.w) * r2[3] + bb;
    }
    if (tid < 128) {
#pragma unroll
      for (int t = 0; t < 4; t++)
        h2buf[(n0 + t) * Dd + j] = ((const float*)&bufB[j])[t] * r2[t];
    }
  }
  __syncthreads();

  float m1[4]; int i1[4];
  {
    if (tid < 256) {
      float bv[4]; int bi[4];
#pragma unroll
      for (int t = 0; t < 4; t++) { bv[t] = val[t]; bi[t] = tid; }
#pragma unroll
      for (int o = 32; o > 0; o >>= 1) {
#pragma unroll
        for (int t = 0; t < 4; t++) {
          float wv = __shfl_xor(bv[t], o, 64);
          int wi = __shfl_xor(bi[t], o, 64);
          if (wv > bv[t] || (wv == bv[t] && wi < bi[t])) { bv[t] = wv; bi[t] = wi; }
        }
      }
      if (lane == 0) {
#pragma unroll
        for (int t = 0; t < 4; t++) { wvS[tid >> 6][t] = bv[t]; wiS[tid >> 6][t] = bi[t]; }
      }
    }
    __syncthreads();
    if (tid < 256) {
#pragma unroll
      for (int t = 0; t < 4; t++) {
        m1[t] = wvS[0][t]; i1[t] = wiS[0][t];
#pragma unroll
        for (int w = 1; w < 4; w++) {
          float cv = wvS[w][t]; int ci = wiS[w][t];
          if (cv > m1[t] || (cv == m1[t] && ci < i1[t])) { m1[t] = cv; i1[t] = ci; }
        }
      }
    }
    __syncthreads();
  }
  float m2[4]; int i2[4];
  {
    if (tid < 256) {
      float bv[4]; int bi[4];
#pragma unroll
      for (int t = 0; t < 4; t++) {
        bv[t] = (tid == i1[t]) ? -INFINITY : val[t];
        bi[t] = tid;
      }
#pragma unroll
      for (int o = 32; o > 0; o >>= 1) {
#pragma unroll
        for (int t = 0; t < 4; t++) {
          float wv = __shfl_xor(bv[t], o, 64);
          int wi = __shfl_xor(bi[t], o, 64);
          if (wv > bv[t] || (wv == bv[t] && wi < bi[t])) { bv[t] = wv; bi[t] = wi; }
        }
      }
      if (lane == 0) {
#pragma unroll
        for (int t = 0; t < 4; t++) { wvS[tid >> 6][t] = bv[t]; wiS[tid >> 6][t] = bi[t]; }
      }
    }
    __syncthreads();
    if (tid < 256) {
#pragma unroll
      for (int t = 0; t < 4; t++) {
        m2[t] = wvS[0][t]; i2[t] = wiS[0][t];
#pragma unroll
        for (int w = 1; w < 4; w++) {
          float cv = wvS[w][t]; int ci = wiS[w][t];
          if (cv > m2[t] || (cv == m2[t] && ci < i2[t])) { m2[t] = cv; i2[t] = ci; }
        }
      }
    }
    __syncthreads();
  }
  {
    if (tid < 256) {
      float v[4];
#pragma unroll
      for (int t = 0; t < 4; t++) v[t] = expf(val[t] - m1[t]);
#pragma unroll
      for (int o = 32; o > 0; o >>= 1) {
#pragma unroll
        for (int t = 0; t < 4; t++) v[t] += __shfl_xor(v[t], o, 64);
      }
      if (lane == 0) {
#pragma unroll
        for (int t = 0; t < 4; t++) zS[tid >> 6][t] = v[t];
      }
    }
    __syncthreads();
  }
  if (tid < 4) {
    int t = tid, tok = n0 + t;
    float Z = zS[0][t] + zS[1][t] + zS[2][t] + zS[3][t];
    float p1 = 1.f / Z;
    float p2 = expf(m2[t] - m1[t]) / Z;
    float s = p1 + p2 + EPSF;
    int e1 = i1[t], e2 = i2[t];
    int s1 = atomicAdd(&cnt[e1], 1); if (s1 > SLOTS - 1) s1 = SLOTS - 1;
    int s2 = atomicAdd(&cnt[e2], 1); if (s2 > SLOTS - 1) s2 = SLOTS - 1;
    int sl1 = e1 * SLOTS + s1, sl2 = e2 * SLOTS + s2;
    slottok[sl1] = tok; slottok[sl2] = tok;
    tokslot[tok * 2] = sl1; tokslot[tok * 2 + 1] = sl2;
    gw[tok * 2] = p1 / s; gw[tok * 2 + 1] = p2 / s;
  }
}

__global__ __launch_bounds__(512) void k_exp(const float* __restrict__ h2buf,
                                             const int* __restrict__ slottok,
                                             const int* __restrict__ cnt,
                                             const float* __restrict__ expW,
                                             float* __restrict__ ybuf) {
  const int e = blockIdx.x;
  int n = cnt[e]; if (n > SLOTS) n = SLOTS;
  if (n == 0) return;
  const int base = e * SLOTS;
  const int tid = threadIdx.x;
  const int j = tid & 127, g = tid >> 7;
  __shared__ __align__(16) float hT[128 * 20];
  const float* Wp = expW + (size_t)e * Dd * Dd + j;
  for (int t0 = 0; t0 < n; t0 += 16) {
    int m = n - t0; if (m > 16) m = 16;
    __syncthreads();
    for (int tt = g; tt < m; tt += 4) {
      int tok = slottok[base + t0 + tt];
      hT[j * 20 + tt] = h2buf[tok * Dd + j];
    }
    __syncthreads();
    float acc[4] = {0, 0, 0, 0};
#pragma unroll 8
    for (int i = 0; i < 128; i++) {
      float w = Wp[i * Dd];
      float4 h4 = *(const float4*)&hT[i * 20 + g * 4];
      acc[0] += h4.x * w; acc[1] += h4.y * w; acc[2] += h4.z * w; acc[3] += h4.w * w;
    }
#pragma unroll
    for (int k = 0; k < 4; k++) {
      int tt = g * 4 + k;
      if (tt < m) ybuf[(size_t)(base + t0 + tt) * Dd + j] = acc[k];
    }
  }
}

__global__ __launch_bounds__(512) void k_post(
    const float* __restrict__ xnbuf, const float* __restrict__ ybuf,
    const int* __restrict__ tokslot, const float* __restrict__ gw,
    const float* __restrict__ m1W, const float* __restrict__ m1b,
    const float* __restrict__ m2W, const float* __restrict__ m2b,
    float* __restrict__ out) {
  const int tid = threadIdx.x;
  const int j = tid & 127, g = tid >> 7;
  const int lane = tid & 63;
  const int n0 = blockIdx.x * TPBo;

  __shared__ float4 y1T[128], y2T[128], inT[128], sT[128];
  __shared__ float4 part[3][128];
  __shared__ float4 rtmp[2];
  __shared__ int sSlot[4][2];
  __shared__ float sWt[4][2];

  if (tid < 4) {
    sSlot[tid][0] = tokslot[(n0 + tid) * 2];
    sSlot[tid][1] = tokslot[(n0 + tid) * 2 + 1];
    sWt[tid][0] = gw[(n0 + tid) * 2];
    sWt[tid][1] = gw[(n0 + tid) * 2 + 1];
  }
  __syncthreads();

  {
    float y1 = ybuf[(size_t)sSlot[g][0] * Dd + j];
    float y2 = ybuf[(size_t)sSlot[g][1] * Dd + j];
    ((float*)&y1T[j])[g] = y1;
    ((float*)&y2T[j])[g] = y2;
    ((float*)&inT[j])[g] = sWt[g][0] * y1 + sWt[g][1] * y2;
  }
  __syncthreads();

  {
    float a0 = 0, a1 = 0, a2 = 0, a3 = 0;
    const float* Wp = (g < 2 ? m1W : m2W) + ((g & 1) * 64) * Dd + j;
#pragma unroll 16
    for (int i = 0; i < 64; i++) {
      float4 h4 = inT[(g & 1) * 64 + i];
      float w = Wp[i * Dd];
      a0 += h4.x * w; a1 += h4.y * w; a2 += h4.z * w; a3 += h4.w * w;
    }
    if (g) part[g - 1][j] = make_float4(a0, a1, a2, a3);
    __syncthreads();
    if (g == 0) {
      float b1 = m1b[j], b2 = m2b[j];
      float4 p0 = part[0][j], p1 = part[1][j], p2 = part[2][j];
      float gv[4], uv[4];
      gv[0] = a0 + p0.x + b1; gv[1] = a1 + p0.y + b1;
      gv[2] = a2 + p0.z + b1; gv[3] = a3 + p0.w + b1;
      uv[0] = p1.x + p2.x + b2; uv[1] = p1.y + p2.y + b2;
      uv[2] = p1.z + p2.z + b2; uv[3] = p1.w + p2.w + b2;
#pragma unroll
      for (int t = 0; t < 4; t++) {
        float sv = gv[t] * sigm(gv[t]) * uv[t];
        ((float*)&sT[j])[t] = sv;
        out[(n0 + t) * Dd + j] = xnbuf[(n0 + t) * Dd + j] + sv;
      }
    }
    __syncthreads();
  }

  if (tid < 128) {
    float v[4];
#pragma unroll
    for (int t = 0; t < 4; t++) {
      float sv = ((const float*)&sT[j])[t];
      float d1 = ((const float*)&y1T[j])[t] - sv;
      float d2 = ((const float*)&y2T[j])[t] - sv;
      v[t] = sWt[t][0] * d1 * d1 + sWt[t][1] * d2 * d2;
    }
#pragma unroll
    for (int o = 32; o > 0; o >>= 1) {
#pragma unroll
      for (int t = 0; t < 4; t++) v[t] += __shfl_xor(v[t], o, 64);
    }
    if (lane == 0) rtmp[tid >> 6] = make_float4(v[0], v[1], v[2], v[3]);
  }
  __syncthreads();
  if (tid < 4) {
    float s = ((const float*)&rtmp[0])[tid] + ((const float*)&rtmp[1])[tid];
    out[NTOK * Dd + n0 + tid] = expf(-s * (1.f / 128.f));
  }
}

// ============================================================================
extern "C" void kernel_launch(void* const* d_in, const int* in_sizes, int n_in,
                              void* d_out, int out_size, void* d_ws, size_t ws_size,
                              hipStream_t stream) {
  float* ws = (float*)d_ws;

  Params p;
  p.x   = (const float*)d_in[0];
  p.g1  = (const float*)d_in[1];
  p.qW  = (const float*)d_in[2];
  p.qb  = (const float*)d_in[3];
  p.kdW = (const float*)d_in[4];
  p.kdb = (const float*)d_in[5];
  p.kuW = (const float*)d_in[6];
  p.kub = (const float*)d_in[7];
  p.oW  = (const float*)d_in[8];
  p.ob  = (const float*)d_in[9];
  p.rot = (const float*)d_in[10];
  p.tqs = (const float*)d_in[11];
  p.s1W = (const float*)d_in[12];
  p.s1b = (const float*)d_in[13];
  p.s2W = (const float*)d_in[14];
  p.s2b = (const float*)d_in[15];
  p.g2  = (const float*)d_in[16];
  p.gateW = (const float*)d_in[17];
  p.gateb = (const float*)d_in[18];
  p.expW  = (const float*)d_in[19];
  p.m1W = (const float*)d_in[20];
  p.m1b = (const float*)d_in[21];
  p.m2W = (const float*)d_in[22];
  p.m2b = (const float*)d_in[23];
  p.out = (float*)d_out;

  p.ctx     = ws;                    // 8192
  p.ksum    = ws + 8192;             // 512
  p.oR      = ws + 8704;             // 16384
  p.bR      = ws + 25088;            // 128
  p.h2buf   = ws + 25216;            // 262144
  p.cnt     = (int*)(ws + 287360);   // 256
  p.slottok = (int*)(ws + 287616);   // 65536
  p.ybuf    = ws + 353152;           // 256*256*128

  void* args[] = {(void*)&p};
  hipError_t err = hipErrorUnknown;

  int nb4 = 0;
  if (hipOccupancyMaxActiveBlocksPerMultiprocessor(
          &nb4, reinterpret_cast<const void*>(&k_fused4), 512, 0) != hipSuccess)
    nb4 = 0;
  if (nb4 >= 2) {
    err = hipLaunchCooperativeKernel((void*)k_fused4, dim3(NTOK / 4), dim3(512),
                                     args, 0u, stream);
  }
  if (err != hipSuccess) {
    int nb8 = 0;
    if (hipOccupancyMaxActiveBlocksPerMultiprocessor(
            &nb8, reinterpret_cast<const void*>(&k_fused8), 512, 0) == hipSuccess &&
        nb8 >= 1) {
      err = hipLaunchCooperativeKernel((void*)k_fused8, dim3(NTOK / 8), dim3(512),
                                       args, 0u, stream);
    }
  }
  if (err == hipSuccess) return;

  // ---- fallback: verified 5-kernel pipeline (old workspace layout) --------
  float* qbuf   = ws;                     // 262144
  float* kvbuf  = ws + 262144;            // 524288
  float* ctx    = ws + 786432;            // 8192
  float* ksum   = ws + 794624;            // 512
  float* h2buf  = ws + 795136;            // 262144
  float* xnbuf  = ws + 1057280;           // 262144
  float* gw     = ws + 1319424;           // 4096
  float* oRb    = ws + 1323520;           // 16384
  float* bRb    = ws + 1339904;           // 128
  int*   cnt     = (int*)(ws + 1373056);  // 256
  int*   tokslot = (int*)(ws + 1373312);  // 4096
  int*   slottok = (int*)(ws + 1377408);  // 65536
  float* ybuf   = ws + 1442944;           // 256*256*128

  k_pre<<<NTOK / 4, 512, 0, stream>>>(p.x, p.g1, p.qW, p.qb, p.kdW, p.kdb, p.kuW, p.kub,
                                      qbuf, kvbuf, ctx, ksum, cnt);
  k_ctx<<<321, 256, 0, stream>>>(kvbuf, ctx, ksum, p.oW, p.ob, p.rot, oRb, bRb);
  k_mid<<<NTOK / 4, 512, 0, stream>>>(p.x, qbuf, ctx, ksum, oRb, bRb, p.tqs,
                                      p.s1W, p.s1b, p.s2W, p.s2b, p.g2, p.gateW, p.gateb,
                                      xnbuf, h2buf, gw, tokslot, slottok, cnt);
  k_exp<<<NE, 512, 0, stream>>>(h2buf, slottok, cnt, p.expW, ybuf);
  k_post<<<NTOK / 4, 512, 0, stream>>>(xnbuf, ybuf, tokslot, gw,
                                       p.m1W, p.m1b, p.m2W, p.m2b, p.out);
}